// Round 5
// baseline (256.657 us; speedup 1.0000x reference)
//
#include <hip/hip_runtime.h>

// out[b, t, n, :] = x[b, (t - shift[n]) % 16, n, :]
// x: (B=16, T=16, N=196, c=768) fp32, contiguous.
//
// shift[n] closed form (m=1): w=n%7, h=n/7, a=w%3, b=h%3:
//   (0,0)->-4 (0,1)->1 (0,2)->2
//   (1,0)->-1 (1,1)-> (n==8 ? 0 : -1)   // sticky inv_state: only i=8 sees inv==0
//   (1,2)->3  (2,0)->-2 (2,1)->-3 (2,2)->4
//
// R7: final cache-matrix cell: NT loads + PLAIN stores, on the R3 gather
// structure. Evidence so far: nt/nt ~79us kernel; cached loads cost +15-19us
// regardless of store mode; plain stores were slightly better than nt stores
// in the cached-load pair (93.5 vs 97). Mechanism tested here: output (154 MB)
// write-allocates into L3, absorbing store bursts / smoothing R-W turnaround,
// while nt loads keep the best-measured read path.
// If null -> permutation's 3KB-granule shuffled side is the floor; revert R3.

typedef float f4 __attribute__((ext_vector_type(4)));

__global__ __launch_bounds__(192) void Rand2dPatchShift_kernel(
        const f4* __restrict__ x, f4* __restrict__ out) {
    const int n  = blockIdx.x;      // 0..195
    const int b  = blockIdx.y;      // 0..15
    const int t0 = blockIdx.z * 4;  // 0,4,8,12

    const int w  = n % 7;
    const int h  = n / 7;
    const int a3 = w % 3;
    const int b3 = h % 3;

    int s;
    if (a3 == 0)      s = (b3 == 0) ? -4 : (b3 == 1 ? 1 : 2);
    else if (a3 == 1) s = (b3 == 0) ? -1 : (b3 == 1 ? ((n == 8) ? 0 : -1) : 3);
    else              s = (b3 == 0) ? -2 : (b3 == 1 ? -3 : 4);

    // element index (f4 units) of (b, t=0, n, threadIdx.x); t-stride = 196*192
    const int base    = (b * 3136 + n) * 192 + threadIdx.x;  // b*16*196 = b*3136
    const int tstride = 196 * 192;                           // 37632

    f4 v[4];
#pragma unroll
    for (int i = 0; i < 4; ++i) {
        const int tsrc = ((t0 + i) - s + 16) & 15;
        v[i] = __builtin_nontemporal_load(&x[base + tsrc * tstride]);  // nt load
    }
#pragma unroll
    for (int i = 0; i < 4; ++i) {
        out[base + (t0 + i) * tstride] = v[i];   // plain store (R7 change)
    }
}

extern "C" void kernel_launch(void* const* d_in, const int* in_sizes, int n_in,
                              void* d_out, int out_size, void* d_ws, size_t ws_size,
                              hipStream_t stream) {
    const f4* x = (const f4*)d_in[0];
    f4* out = (f4*)d_out;

    dim3 grid(196, 16, 4);  // (n, b, t-quarter) -> 12544 blocks = 49/CU exactly
    dim3 block(192);        // 3 waves, one float4 lane per thread, 4 t's each
    Rand2dPatchShift_kernel<<<grid, block, 0, stream>>>(x, out);
}

// Round 6
// 252.938 us; speedup vs baseline: 1.0147x; 1.0147x over previous
//
#include <hip/hip_runtime.h>

// out[b, t, n, :] = x[b, (t - shift[n]) % 16, n, :]
// x: (B=16, T=16, N=196, c=768) fp32, contiguous.
//
// shift[n] closed form (m=1): w=n%7, h=n/7, a=w%3, b=h%3:
//   (0,0)->-4 (0,1)->1 (0,2)->2
//   (1,0)->-1 (1,1)-> (n==8 ? 0 : -1)   // sticky inv_state: only i=8 sees inv==0
//   (1,2)->3  (2,0)->-2 (2,1)->-3 (2,2)->4
//
// R8 (FINAL): revert to the best-measured configuration -- the original
// 16-t-per-block, nt-load/nt-store gather (251.3/252.2 us, the two best
// recorded). Session conclusions (all within-harness A/B):
//   - cache matrix: nt/nt 253.4 > nt/plain 256.7 > plain/plain 268.7 >
//     cached/nt 270.7. Any cache allocation on either stream loses.
//   - direction: gather == scatter (253.5 vs 253.3) -- the permutation tax is
//     one-sided-shuffle-at-3KB-granule, independent of which side shuffles.
//   - occupancy/balance/reg-window: null (12.25 vs 49 blocks/CU identical).
// Ceiling: timed region = 2 fixed harness fills (~186us) + kernel (~66us =
// ~4.7 TB/s on 308 MB). Copy roofline 6.29 TB/s would need granule > 3KB,
// impossible here (shift changes every n). This is the op's memory floor.

typedef float f4 __attribute__((ext_vector_type(4)));

__global__ __launch_bounds__(192) void Rand2dPatchShift_kernel(
        const f4* __restrict__ x, f4* __restrict__ out) {
    const int n = blockIdx.x;   // 0..195
    const int b = blockIdx.y;   // 0..15

    const int w  = n % 7;
    const int h  = n / 7;
    const int a3 = w % 3;
    const int b3 = h % 3;

    int s;
    if (a3 == 0)      s = (b3 == 0) ? -4 : (b3 == 1 ? 1 : 2);
    else if (a3 == 1) s = (b3 == 0) ? -1 : (b3 == 1 ? ((n == 8) ? 0 : -1) : 3);
    else              s = (b3 == 0) ? -2 : (b3 == 1 ? -3 : 4);

    // base of (b, t=0, n, :) in float4 units; row stride over t is 196*192
    const long long base = ((long long)b * 16 * 196 + n) * 192 + threadIdx.x;
    const long long tstride = 196 * 192;

    f4 v[16];
#pragma unroll
    for (int t = 0; t < 16; ++t) {
        const int tsrc = (t - s + 16) & 15;
        v[t] = __builtin_nontemporal_load(&x[base + (long long)tsrc * tstride]);
    }
#pragma unroll
    for (int t = 0; t < 16; ++t) {
        __builtin_nontemporal_store(v[t], &out[base + (long long)t * tstride]);
    }
}

extern "C" void kernel_launch(void* const* d_in, const int* in_sizes, int n_in,
                              void* d_out, int out_size, void* d_ws, size_t ws_size,
                              hipStream_t stream) {
    const f4* x = (const f4*)d_in[0];
    f4* out = (f4*)d_out;

    dim3 grid(196, 16);   // (n, b)
    dim3 block(192);      // 3 waves, one float4 lane per thread, 16 t's each
    Rand2dPatchShift_kernel<<<grid, block, 0, stream>>>(x, out);
}